// Round 1
// baseline (444.805 us; speedup 1.0000x reference)
//
#include <hip/hip_runtime.h>
#include <hip/hip_bf16.h>

// BinaryLSTMCell fused kernel for MI355X (gfx950).
// B=65536, D=256, U=256.  out = [h_new | h_new | c_new], f32.
//
// Strategy: x_all = ht(inputs @ binW), r_all = clip(h) @ binRW computed in one
// fused kernel via f16 MFMA with 2-term (hi+lo) f16 split of the f32 LHS.
// Weights binarized to +-1 f16 (exact) and transposed by a prep kernel into d_ws.

#define NB 65536
#define NU 256

typedef _Float16 f16x8 __attribute__((ext_vector_type(8)));
typedef float f32x16 __attribute__((ext_vector_type(16)));

#define ROWB 160   // padded LDS row stride (bytes): 128B data + 32B pad
#define A_X_OFF 0              // 128 rows * 160B = 20480
#define A_R_OFF 20480
#define W_X_OFF 40960          // 256 rows * 160B = 40960
#define W_R_OFF 81920          // ends 122880
#define LDS_BYTES 131072       // epilogue reuses [0,131072) as f32[4][128][64]

// Row-padded + chunk-XOR swizzle: 8 consecutive rows -> 8 distinct 16B bank slots.
__device__ __forceinline__ int swzoff(int row, int c) {
  return row * ROWB + (((c ^ (row >> 2)) & 7) << 4);
}

__device__ __forceinline__ float htanh(float x) { return fminf(1.f, fmaxf(-1.f, x)); }

// Split 8 f32 into f16 hi (chunk chi..), f16 lo (chunk chi+4..) and store to LDS.
template <bool CLIP>
__device__ __forceinline__ void splitStore(char* base, int row, int chi,
                                           float4 a, float4 b) {
  float xs[8] = {a.x, a.y, a.z, a.w, b.x, b.y, b.z, b.w};
  f16x8 hv, lv;
#pragma unroll
  for (int i = 0; i < 8; ++i) {
    float x = xs[i];
    if (CLIP) x = htanh(x);
    _Float16 hf = (_Float16)x;        // v_cvt_f16_f32 (RNE)
    float r = x - (float)hf;          // exact residual
    hv[i] = hf;
    lv[i] = (_Float16)r;
  }
  *(f16x8*)(base + swzoff(row, chi))     = hv;
  *(f16x8*)(base + swzoff(row, chi + 4)) = lv;
}

// Binarize (w>=0 ? +1 : -1) both weight matrices to f16 and transpose:
// Wt[n][k] = sign(kernel[k][n]),  n in [0,1024), k in [0,256).
__global__ void prep_w(const float* __restrict__ Kf, const float* __restrict__ RKf,
                       unsigned short* __restrict__ Wt, unsigned short* __restrict__ RWt) {
  __shared__ unsigned short tile[64][68];
  const int mat = blockIdx.x >> 6;
  const int tb = blockIdx.x & 63;
  const int k0 = (tb & 3) << 6;   // 4 k-tiles of 64
  const int n0 = (tb >> 2) << 6;  // 16 n-tiles of 64
  const float* src = mat ? RKf : Kf;
  unsigned short* dst = mat ? RWt : Wt;
  const int tid = threadIdx.x;
  const int r = tid >> 2;
  const int c0 = (tid & 3) << 4;
#pragma unroll
  for (int i = 0; i < 16; i += 4) {
    float4 v = *(const float4*)(src + (k0 + r) * 1024 + n0 + c0 + i);
    tile[r][c0 + i + 0] = (v.x >= 0.f) ? 0x3C00u : 0xBC00u;
    tile[r][c0 + i + 1] = (v.y >= 0.f) ? 0x3C00u : 0xBC00u;
    tile[r][c0 + i + 2] = (v.z >= 0.f) ? 0x3C00u : 0xBC00u;
    tile[r][c0 + i + 3] = (v.w >= 0.f) ? 0x3C00u : 0xBC00u;
  }
  __syncthreads();
#pragma unroll
  for (int i = 0; i < 16; i += 2) {
    unsigned wv = (unsigned)tile[c0 + i][r] | ((unsigned)tile[c0 + i + 1][r] << 16);
    *(unsigned*)(dst + (n0 + r) * 256 + k0 + c0 + i) = wv;
  }
}

// Main fused kernel.
// Block: 512 thr (8 waves: wm x wu x wside), tile 128 rows x 64 u, both GEMMs.
// K loop: 8 steps of 32 f32-k; A staged as f16 hi|lo (bf16-free), W rows hold 2 steps.
__global__ __launch_bounds__(512, 2)
void blstm_main(const float* __restrict__ xin, const float* __restrict__ hin,
                const float* __restrict__ cin, const unsigned short* __restrict__ Wt,
                const unsigned short* __restrict__ RWt, float* __restrict__ out) {
  extern __shared__ char smem[];
  const int bid = blockIdx.x;
  const int swz = (bid & 7) * 256 + (bid >> 3);   // XCD-aware swizzle (2048 % 8 == 0)
  const int m0 = (swz >> 2) << 7;                 // 512 m-blocks of 128
  const int u0 = (swz & 3) << 6;                  // 4 u-blocks of 64

  const int tid = threadIdx.x;
  const int lane = tid & 63;
  const int w = tid >> 6;
  const int wm = w >> 2, wu = (w >> 1) & 1, wside = w & 1;  // wside: 0=x, 1=r
  const int lrow = lane & 31, lhalf = lane >> 5;

  // A staging: thread -> (row = tid>>2, f32-k quadpair = (tid&3)*8)
  const int sArow = tid >> 2;
  const int sAc = tid & 3;
  const float* axp = xin + (m0 + sArow) * 256 + (sAc << 3);
  const float* arp = hin + (m0 + sArow) * 256 + (sAc << 3);

  // W staging: 256 thr per matrix, one LDS row (gate*64+u) each; 64 f16 k per pair.
  const int sWmat = tid >> 8;
  const int sWn = tid & 255;
  const unsigned short* wsrc =
      (sWmat ? RWt : Wt) + (((sWn >> 6) << 8) + u0 + (sWn & 63)) * 256;
  char* wdst = smem + (sWmat ? W_R_OFF : W_X_OFF);

  f32x16 acc[2][4] = {};

  float4 pax0, pax1, par0, par1;
  uint4 pw[8];

  // prologue prefetch (step 0 A, pair 0 W)
  pax0 = *(const float4*)(axp);
  pax1 = *(const float4*)(axp + 4);
  par0 = *(const float4*)(arp);
  par1 = *(const float4*)(arp + 4);
#pragma unroll
  for (int i = 0; i < 8; ++i) pw[i] = *(const uint4*)(wsrc + i * 8);

  const char* abase = smem + (wside ? A_R_OFF : A_X_OFF);
  const char* wbase = smem + (wside ? W_R_OFF : W_X_OFF);

  for (int s = 0; s < 8; ++s) {
    // ---- stage phase: convert prefetched A, write W on even steps ----
    splitStore<false>(smem + A_X_OFF, sArow, sAc, pax0, pax1);
    splitStore<true >(smem + A_R_OFF, sArow, sAc, par0, par1);
    if ((s & 1) == 0) {
#pragma unroll
      for (int i = 0; i < 8; ++i)
        *(uint4*)(wdst + swzoff(sWn, i)) = pw[i];
    }
    __syncthreads();

    // ---- issue next-step global loads so they fly during compute ----
    if (s < 7) {
      pax0 = *(const float4*)(axp + (s + 1) * 32);
      pax1 = *(const float4*)(axp + (s + 1) * 32 + 4);
      par0 = *(const float4*)(arp + (s + 1) * 32);
      par1 = *(const float4*)(arp + (s + 1) * 32 + 4);
      if (s & 1) {
        const int p = (s + 1) >> 1;
#pragma unroll
        for (int i = 0; i < 8; ++i)
          pw[i] = *(const uint4*)(wsrc + (p << 6) + i * 8);
      }
    }

    // ---- compute: 32 x v_mfma_f32_32x32x16_f16 per wave ----
    const int cs = (s & 1) << 2;   // W chunk base: which half of the k-pair row
#pragma unroll
    for (int j = 0; j < 2; ++j) {  // two K16 units per 32-k step
      f16x8 wf[4];
#pragma unroll
      for (int g = 0; g < 4; ++g)
        wf[g] = *(const f16x8*)(wbase +
                 swzoff((g << 6) + (wu << 5) + lrow, cs + (j << 1) + lhalf));
#pragma unroll
      for (int hl = 0; hl < 2; ++hl) {  // hi then lo A, same W frag
        f16x8 af[2];
#pragma unroll
        for (int mf = 0; mf < 2; ++mf)
          af[mf] = *(const f16x8*)(abase +
                   swzoff((wm << 6) + (mf << 5) + lrow, (hl << 2) + (j << 1) + lhalf));
#pragma unroll
        for (int mf = 0; mf < 2; ++mf)
#pragma unroll
          for (int g = 0; g < 4; ++g)
            acc[mf][g] = __builtin_amdgcn_mfma_f32_32x32x16_f16(af[mf], wf[g],
                                                                acc[mf][g], 0, 0, 0);
      }
    }
    __syncthreads();
  }

  // ---- epilogue: r-waves publish r_all; x-waves combine gates and write ----
  // C/D layout (verified m74/m101): col = lane&31, row = (reg&3)+8*(reg>>2)+4*(lane>>5)
  float* epi = (float*)smem;   // [4 gates][128 rows][64 u] f32
  if (wside) {
#pragma unroll
    for (int mf = 0; mf < 2; ++mf)
#pragma unroll
      for (int g = 0; g < 4; ++g)
#pragma unroll
        for (int r = 0; r < 16; ++r) {
          const int row = (wm << 6) + (mf << 5) + (lhalf << 2) + (r & 3) + ((r >> 2) << 3);
          const int ul = (wu << 5) + lrow;
          epi[((g << 7) + row) * 64 + ul] = acc[mf][g][r];
        }
  }
  __syncthreads();
  if (!wside) {
    const int ul = (wu << 5) + lrow;
#pragma unroll
    for (int mf = 0; mf < 2; ++mf)
#pragma unroll
      for (int r = 0; r < 16; ++r) {
        const int row = (wm << 6) + (mf << 5) + (lhalf << 2) + (r & 3) + ((r >> 2) << 3);
        const int grow = m0 + row, gu = u0 + ul;
        const float xi = htanh(acc[mf][0][r]);   // x_all = ht(inputs @ binW)
        const float xf = htanh(acc[mf][1][r]);
        const float xc = htanh(acc[mf][2][r]);
        const float xo = htanh(acc[mf][3][r]);
        const float ri = epi[(0 * 128 + row) * 64 + ul];
        const float rf = epi[(1 * 128 + row) * 64 + ul];
        const float rc = epi[(2 * 128 + row) * 64 + ul];
        const float ro = epi[(3 * 128 + row) * 64 + ul];
        // NOTE the reference's gate crossing: f uses x_i + r_f, i uses x_f + r_i.
        const float fg   = htanh(xi + rf);
        const float ig   = htanh(xf + ri);
        const float cand = htanh(xc + rc);
        const float og   = htanh(xo + ro);
        const float ctm  = htanh(cin[grow * 256 + gu]);
        const float cn = fg * ctm + ig * cand;
        const float hn = htanh(og * htanh(cn));
        const int o1 = grow * 256 + gu;
        out[o1] = hn;
        out[NB * 256 + o1] = hn;
        out[2 * NB * 256 + o1] = cn;
      }
  }
}

extern "C" void kernel_launch(void* const* d_in, const int* in_sizes, int n_in,
                              void* d_out, int out_size, void* d_ws, size_t ws_size,
                              hipStream_t stream) {
  const float* xin = (const float*)d_in[0];
  const float* hin = (const float*)d_in[1];
  const float* cin = (const float*)d_in[2];
  const float* kf  = (const float*)d_in[3];
  const float* rkf = (const float*)d_in[4];
  float* out = (float*)d_out;

  unsigned short* Wt  = (unsigned short*)d_ws;          // 1024x256 f16 = 512 KB
  unsigned short* RWt = Wt + 1024 * 256;                // next 512 KB

  (void)hipFuncSetAttribute((const void*)blstm_main,
                            hipFuncAttributeMaxDynamicSharedMemorySize, LDS_BYTES);

  prep_w<<<128, 256, 0, stream>>>(kf, rkf, Wt, RWt);
  blstm_main<<<2048, 512, LDS_BYTES, stream>>>(xin, hin, cin, Wt, RWt, out);
}

// Round 2
// 204.288 us; speedup vs baseline: 2.1773x; 2.1773x over previous
//
#include <hip/hip_runtime.h>

// BinaryLSTMCell fused kernel v2 for MI355X (gfx950).
// B=65536, D=256, U=256. out = [h_new | h_new | c_new], f32.
//
// v1 post-mortem: 444us, MfmaUtil 12%, Occupancy 20% -> latency-bound:
// acc=128 AGPR capped 2 waves/SIMD, 128KB LDS capped 1 block/CU, lockstep.
// v2: per-wave both-sides tile (no big exchange), gates split across waves,
// acc=64, 32KB LDS, 3 blocks/CU, W as pre-built L2-resident MFMA fragments
// loaded straight from global (no W LDS, no W staging barrier).

#define NB 65536

typedef _Float16 f16x8 __attribute__((ext_vector_type(8)));
typedef float f32x16 __attribute__((ext_vector_type(16)));

__device__ __forceinline__ float htanh(float x) { return fminf(1.f, fmaxf(-1.f, x)); }

// ---------------------------------------------------------------------------
// prep: binarize both weight matrices into 1024 pre-built MFMA B-fragments.
// Fragment id = (((kt*2 + j)*2 + side)*4 + gate)*8 + u32,  1KB each:
//   lane l holds 16B: n = base + (l&31), k = kt*32 + j*16 + (l>>5)*8 + e.
// ---------------------------------------------------------------------------
__global__ void prep_w(const float* __restrict__ Kf, const float* __restrict__ RKf,
                       unsigned short* __restrict__ wfrag) {
  __shared__ unsigned short sgn[32][72];
  const int b = blockIdx.x;            // 256 blocks
  const int side = b >> 7, kt = (b >> 4) & 7, nt = b & 15;
  const float* M = side ? RKf : Kf;
  const int t = threadIdx.x;

  // load 32k x 64n tile, coalesced, store signs
  {
    const int k = t >> 3, n8 = (t & 7) << 3;
    const float* p = M + (kt * 32 + k) * 1024 + nt * 64 + n8;
    float4 v0 = *(const float4*)p;
    float4 v1 = *(const float4*)(p + 4);
    float xs[8] = {v0.x, v0.y, v0.z, v0.w, v1.x, v1.y, v1.z, v1.w};
#pragma unroll
    for (int i = 0; i < 8; ++i)
      sgn[k][n8 + i] = (xs[i] >= 0.f) ? 0x3C00u : 0xBC00u;
  }
  __syncthreads();

  // emit 4 fragments (j x u32-half), 64 lanes each
  const int fl = t >> 6, l = t & 63;
  const int j = fl >> 1, uh = fl & 1;
  const int nloc = uh * 32 + (l & 31);
  const int kloc = j * 16 + (l >> 5) * 8;
  unsigned short o[8];
#pragma unroll
  for (int e = 0; e < 8; ++e) o[e] = sgn[kloc + e][nloc];
  const int ng = nt * 64 + nloc;                 // 0..1023
  const int gate = ng >> 8, u32 = (ng >> 5) & 7;
  const int fragid = (((kt * 2 + j) * 2 + side) * 4 + gate) * 8 + u32;
  uint4 ov;
  ov.x = (unsigned)o[0] | ((unsigned)o[1] << 16);
  ov.y = (unsigned)o[2] | ((unsigned)o[3] << 16);
  ov.z = (unsigned)o[4] | ((unsigned)o[5] << 16);
  ov.w = (unsigned)o[6] | ((unsigned)o[7] << 16);
  *(uint4*)((char*)wfrag + fragid * 1024 + l * 16) = ov;
}

// ---------------------------------------------------------------------------
// main: 256 thr (4 waves = 2 wu x 2 wg), tile 32 rows x 64 u, both sides.
// K loop: 8 steps of 32 f32-k, A double-buffered in LDS as f16 hi|lo,
// W fragments direct from global (L2). One barrier per step.
// ---------------------------------------------------------------------------
__global__ __launch_bounds__(256, 3)
void blstm_main(const float* __restrict__ xin, const float* __restrict__ hin,
                const float* __restrict__ cin, const unsigned short* __restrict__ wfrag,
                float* __restrict__ out) {
  __shared__ char smem[32768];   // [0,16K): A dbuf (2 x 8KB), [16K,32K): exchange

  const int bid = blockIdx.x;
  const int swz = (bid & 7) * 1024 + (bid >> 3);   // XCD swizzle, 8192 % 8 == 0
  const int mb = swz >> 2, ub = swz & 3;
  const int m0 = mb << 5;                           // 32-row strip
  const int u0 = ub << 6;                           // 64-u block

  const int tid = threadIdx.x;
  const int lane = tid & 63;
  const int w = tid >> 6;
  const int wu = w & 1, wg = w >> 1;                // wg: gates {2wg, 2wg+1}
  const int l31 = lane & 31, lh = lane >> 5;

  // ---- A staging role: side/row/quad for this thread ----
  const int sSide = tid >> 7;                       // 0 = x, 1 = h
  const int sRow = (tid & 127) >> 2;                // 0..31
  const int sQ = tid & 3;                           // 8-f32 quad
  const float* aPtr = (sSide ? hin : xin) + (m0 + sRow) * 256 + (sQ << 3);
  char* const aWr = smem + sSide * 4096 + sRow * 128;
  const int swzHi = ((sQ ^ (sRow & 7)) << 4);
  const int swzLo = (((sQ + 4) ^ (sRow & 7)) << 4);

  // ---- W fragment base addresses (per nf = side*2 + gidx, per j) ----
  const char* const wbase = (const char*)wfrag + lane * 16;
  // fragid(s,j,nf): (((s*2+j)*2+side)*4 + (wg*2+gidx))*8 + (ub*2+wu)

  f32x16 acc[4] = {};   // nf = side*2 + gidx

  float4 a0 = *(const float4*)(aPtr);
  float4 a1 = *(const float4*)(aPtr + 4);

  for (int s = 0; s < 8; ++s) {
    // ---- convert prefetched A regs -> LDS buf[s&1] ----
    {
      char* wr = aWr + (s & 1) * 8192;
      float xs[8] = {a0.x, a0.y, a0.z, a0.w, a1.x, a1.y, a1.z, a1.w};
      f16x8 hv, lv;
#pragma unroll
      for (int i = 0; i < 8; ++i) {
        float x = xs[i];
        if (sSide) x = htanh(x);
        _Float16 hf = (_Float16)x;
        hv[i] = hf;
        lv[i] = (_Float16)(x - (float)hf);
      }
      *(f16x8*)(wr + swzHi) = hv;
      *(f16x8*)(wr + swzLo) = lv;
    }

    // ---- issue next A loads + this step's W fragment loads ----
    f16x8 wfr[2][4];
#pragma unroll
    for (int j = 0; j < 2; ++j)
#pragma unroll
      for (int nf = 0; nf < 4; ++nf) {
        const int side = nf >> 1, gate = wg * 2 + (nf & 1);
        const int fragid = (((s * 2 + j) * 2 + side) * 4 + gate) * 8 + (ub * 2 + wu);
        wfr[j][nf] = *(const f16x8*)(wbase + fragid * 1024);
      }
    if (s < 7) {
      a0 = *(const float4*)(aPtr + (s + 1) * 32);
      a1 = *(const float4*)(aPtr + (s + 1) * 32 + 4);
    }

    __syncthreads();

    // ---- compute: 8 af LDS reads + 16 MFMA ----
    const char* rd = smem + (s & 1) * 8192;
#pragma unroll
    for (int j = 0; j < 2; ++j) {
#pragma unroll
      for (int hl = 0; hl < 2; ++hl) {
        f16x8 af[2];
#pragma unroll
        for (int side = 0; side < 2; ++side)
          af[side] = *(const f16x8*)(rd + side * 4096 + l31 * 128 +
                       ((((hl << 2) | (j << 1) | lh) ^ (l31 & 7)) << 4));
#pragma unroll
        for (int nf = 0; nf < 4; ++nf)
          acc[nf] = __builtin_amdgcn_mfma_f32_32x32x16_f16(af[nf >> 1], wfr[j][nf],
                                                           acc[nf], 0, 0, 0);
      }
    }
  }

  // ---- epilogue ----
  // C/D layout (verified): col = lane&31, row = (reg&3) + 8*(reg>>2) + 4*(lane>>5)
  float* ex = (float*)(smem + 16384 + wu * 8192);   // [cand 4KB | og 4KB] per wu

  if (wg == 1) {
    // gates {2,3}: cand = ht(ht(x_c)+r_c), og = ht(ht(x_o)+r_o)
    float4 c4[4], o4[4];
#pragma unroll
    for (int r = 0; r < 16; ++r) {
      float cand = htanh(htanh(acc[0][r]) + acc[2][r]);
      float og   = htanh(htanh(acc[1][r]) + acc[3][r]);
      ((float*)&c4[r >> 2])[r & 3] = cand;
      ((float*)&o4[r >> 2])[r & 3] = og;
    }
#pragma unroll
    for (int c = 0; c < 4; ++c) {
      *(float4*)((char*)ex + c * 1024 + lane * 16) = c4[c];
      *(float4*)((char*)ex + 4096 + c * 1024 + lane * 16) = o4[c];
    }
  }
  __syncthreads();
  if (wg == 0) {
    float4 c4[4], o4[4];
#pragma unroll
    for (int c = 0; c < 4; ++c) {
      c4[c] = *(const float4*)((const char*)ex + c * 1024 + lane * 16);
      o4[c] = *(const float4*)((const char*)ex + 4096 + c * 1024 + lane * 16);
    }
#pragma unroll
    for (int r = 0; r < 16; ++r) {
      const int row = (r & 3) + ((r >> 2) << 3) + (lh << 2);
      const int grow = m0 + row;
      const int gu = u0 + wu * 32 + l31;
      // gates {0,1}: f = ht(ht(x_i)+r_f), i = ht(ht(x_f)+r_i)  (note crossing)
      const float fg = htanh(htanh(acc[0][r]) + acc[3][r]);
      const float ig = htanh(htanh(acc[1][r]) + acc[2][r]);
      const float cand = ((const float*)&c4[r >> 2])[r & 3];
      const float og   = ((const float*)&o4[r >> 2])[r & 3];
      const float ct = htanh(cin[grow * 256 + gu]);
      const float cn = fg * ct + ig * cand;
      const float hn = htanh(og * htanh(cn));
      const int o1 = grow * 256 + gu;
      out[o1] = hn;
      out[NB * 256 + o1] = hn;
      out[2 * NB * 256 + o1] = cn;
    }
  }
}

extern "C" void kernel_launch(void* const* d_in, const int* in_sizes, int n_in,
                              void* d_out, int out_size, void* d_ws, size_t ws_size,
                              hipStream_t stream) {
  const float* xin = (const float*)d_in[0];
  const float* hin = (const float*)d_in[1];
  const float* cin = (const float*)d_in[2];
  const float* kf  = (const float*)d_in[3];
  const float* rkf = (const float*)d_in[4];
  float* out = (float*)d_out;

  unsigned short* wfrag = (unsigned short*)d_ws;    // 1024 frags x 1KB = 1MB

  prep_w<<<256, 256, 0, stream>>>(kf, rkf, wfrag);
  blstm_main<<<8192, 256, 0, stream>>>(xin, hin, cin, wfrag, out);
}

// Round 3
// 204.219 us; speedup vs baseline: 2.1781x; 1.0003x over previous
//
#include <hip/hip_runtime.h>

// BinaryLSTMCell fused kernel v3 for MI355X (gfx950).
// B=65536, D=256, U=256. out = [h_new | h_new | c_new], f32.
//
// v2 post-mortem: 232us, MfmaUtil 25% == achieved TF fraction -> stall-bound.
// Cause: __syncthreads() drains vmcnt(0) every step, killing the W/A prefetch
// issued just before it (m97 pathology).
// v3: raw s_barrier + lgkmcnt(0)-only drain (m201 pattern) so global loads
// stay in flight across barriers with compiler-counted vmcnt at use; W-frag
// reload placed after last MFMA use; fragment layout reordered so per-(s,j)
// wave frags are at static offsets {0,1K,2K,3K} (address VALU ~2 adds/step).

#define NB 65536

typedef _Float16 f16x8 __attribute__((ext_vector_type(8)));
typedef float f32x16 __attribute__((ext_vector_type(16)));

__device__ __forceinline__ float htanh(float x) { return fminf(1.f, fmaxf(-1.f, x)); }

// ---------------------------------------------------------------------------
// prep: binarize both weight matrices into 1024 pre-built MFMA B-fragments.
// fragid = (((kt*2 + j)*8 + u32)*4 + gate)*2 + side, 1KB each:
//   lane l holds 16B: n = gate*256+u32*32 + (l&31), k = kt*32 + j*16 + (l>>5)*8 + e.
// ---------------------------------------------------------------------------
__global__ void prep_w(const float* __restrict__ Kf, const float* __restrict__ RKf,
                       unsigned short* __restrict__ wfrag) {
  __shared__ unsigned short sgn[32][72];
  const int b = blockIdx.x;            // 256 blocks
  const int side = b >> 7, kt = (b >> 4) & 7, nt = b & 15;
  const float* M = side ? RKf : Kf;
  const int t = threadIdx.x;

  // load 32k x 64n tile, coalesced, store signs
  {
    const int k = t >> 3, n8 = (t & 7) << 3;
    const float* p = M + (kt * 32 + k) * 1024 + nt * 64 + n8;
    float4 v0 = *(const float4*)p;
    float4 v1 = *(const float4*)(p + 4);
    float xs[8] = {v0.x, v0.y, v0.z, v0.w, v1.x, v1.y, v1.z, v1.w};
#pragma unroll
    for (int i = 0; i < 8; ++i)
      sgn[k][n8 + i] = (xs[i] >= 0.f) ? 0x3C00u : 0xBC00u;
  }
  __syncthreads();

  // emit 4 fragments (j x u32-half), 64 lanes each
  const int fl = t >> 6, l = t & 63;
  const int j = fl >> 1, uh = fl & 1;
  const int nloc = uh * 32 + (l & 31);
  const int kloc = j * 16 + (l >> 5) * 8;
  unsigned short o[8];
#pragma unroll
  for (int e = 0; e < 8; ++e) o[e] = sgn[kloc + e][nloc];
  const int ng = nt * 64 + nloc;                 // 0..1023
  const int gate = ng >> 8, u32 = (ng >> 5) & 7;
  const int fragid = (((kt * 2 + j) * 8 + u32) * 4 + gate) * 2 + side;
  uint4 ov;
  ov.x = (unsigned)o[0] | ((unsigned)o[1] << 16);
  ov.y = (unsigned)o[2] | ((unsigned)o[3] << 16);
  ov.z = (unsigned)o[4] | ((unsigned)o[5] << 16);
  ov.w = (unsigned)o[6] | ((unsigned)o[7] << 16);
  *(uint4*)((char*)wfrag + fragid * 1024 + l * 16) = ov;
}

// ---------------------------------------------------------------------------
// main: 256 thr (4 waves = 2 wu x 2 wg), tile 32 rows x 64 u, both sides.
// K loop: 8 steps of 32 f32-k, A double-buffered in LDS as f16 hi|lo,
// W fragments direct from global (L2). One raw barrier per step.
// ---------------------------------------------------------------------------
__global__ __launch_bounds__(256, 3)
void blstm_main(const float* __restrict__ xin, const float* __restrict__ hin,
                const float* __restrict__ cin, const unsigned short* __restrict__ wfrag,
                float* __restrict__ out) {
  __shared__ char smem[32768];   // [0,16K): A dbuf (2 x 8KB), [16K,32K): exchange

  const int bid = blockIdx.x;
  const int swz = (bid & 7) * 1024 + (bid >> 3);   // XCD swizzle, 8192 % 8 == 0
  const int mb = swz >> 2, ub = swz & 3;
  const int m0 = mb << 5;                           // 32-row strip
  const int u0 = ub << 6;                           // 64-u block

  const int tid = threadIdx.x;
  const int lane = tid & 63;
  const int w = tid >> 6;
  const int wu = w & 1, wg = w >> 1;                // wg: gates {2wg, 2wg+1}
  const int l31 = lane & 31, lh = lane >> 5;

  // ---- A staging role: side/row/quad for this thread ----
  const int sSide = tid >> 7;                       // 0 = x, 1 = h (wave-uniform)
  const int sRow = (tid & 127) >> 2;                // 0..31
  const int sQ = tid & 3;                           // 8-f32 quad
  const float* aPtr = (sSide ? hin : xin) + (m0 + sRow) * 256 + (sQ << 3);
  char* const aWr = smem + sSide * 4096 + sRow * 128;
  const int swzHi = ((sQ ^ (sRow & 7)) << 4);
  const int swzLo = (((sQ + 4) ^ (sRow & 7)) << 4);

  // ---- W fragment base: runtime part folded once ----
  // byte(fragid) = (S*2+j)*65536 + uw*8192 + wg*4096 + gidx*2048 + side*1024
  const char* const wq = (const char*)wfrag + ((ub * 2 + wu) << 13) + (wg << 12) + lane * 16;

  f32x16 acc[4] = {};   // nf = side*2 + gidx
  f16x8 wfr[2][4];
  float4 a0, a1;

  // ---- prologue: A(0) then W(0) ----
  a0 = *(const float4*)(aPtr);
  a1 = *(const float4*)(aPtr + 4);
#define WLOAD(S) do {                                                     \
    const char* p0_ = wq + (S) * 2 * 65536;                               \
    const char* p1_ = wq + ((S) * 2 + 1) * 65536;                         \
    wfr[0][0] = *(const f16x8*)(p0_);                                     \
    wfr[0][1] = *(const f16x8*)(p0_ + 2048);                              \
    wfr[0][2] = *(const f16x8*)(p0_ + 1024);                              \
    wfr[0][3] = *(const f16x8*)(p0_ + 3072);                              \
    wfr[1][0] = *(const f16x8*)(p1_);                                     \
    wfr[1][1] = *(const f16x8*)(p1_ + 2048);                              \
    wfr[1][2] = *(const f16x8*)(p1_ + 1024);                              \
    wfr[1][3] = *(const f16x8*)(p1_ + 3072);                              \
  } while (0)
  WLOAD(0);

#define STEP(S) do {                                                      \
    /* stage: grab cur A, issue next A loads, convert -> LDS buf[S&1] */  \
    float4 c0_ = a0, c1_ = a1;                                            \
    if ((S) < 7) {                                                        \
      a0 = *(const float4*)(aPtr + ((S) + 1) * 32);                       \
      a1 = *(const float4*)(aPtr + ((S) + 1) * 32 + 4);                   \
    }                                                                     \
    {                                                                     \
      char* wr_ = aWr + ((S) & 1) * 8192;                                 \
      float xs_[8] = {c0_.x, c0_.y, c0_.z, c0_.w, c1_.x, c1_.y, c1_.z, c1_.w}; \
      f16x8 hv_, lv_;                                                     \
      _Pragma("unroll")                                                   \
      for (int i_ = 0; i_ < 8; ++i_) {                                    \
        float x_ = xs_[i_];                                               \
        if (sSide) x_ = htanh(x_);                                        \
        _Float16 hf_ = (_Float16)x_;                                      \
        hv_[i_] = hf_;                                                    \
        lv_[i_] = (_Float16)(x_ - (float)hf_);                            \
      }                                                                   \
      *(f16x8*)(wr_ + swzHi) = hv_;                                       \
      *(f16x8*)(wr_ + swzLo) = lv_;                                       \
    }                                                                     \
    asm volatile("s_waitcnt lgkmcnt(0)" ::: "memory");                    \
    __builtin_amdgcn_s_barrier();                                         \
    __builtin_amdgcn_sched_barrier(0);                                    \
    asm volatile("" ::: "memory");                                        \
    {                                                                     \
      const char* rd_ = smem + ((S) & 1) * 8192;                          \
      _Pragma("unroll")                                                   \
      for (int j_ = 0; j_ < 2; ++j_) {                                    \
        _Pragma("unroll")                                                 \
        for (int hl_ = 0; hl_ < 2; ++hl_) {                               \
          f16x8 af_[2];                                                   \
          _Pragma("unroll")                                               \
          for (int sd_ = 0; sd_ < 2; ++sd_)                               \
            af_[sd_] = *(const f16x8*)(rd_ + sd_ * 4096 + l31 * 128 +     \
                         ((((hl_ << 2) | (j_ << 1) | lh) ^ (l31 & 7)) << 4)); \
          _Pragma("unroll")                                               \
          for (int nf_ = 0; nf_ < 4; ++nf_)                               \
            acc[nf_] = __builtin_amdgcn_mfma_f32_32x32x16_f16(            \
                af_[nf_ >> 1], wfr[j_][nf_], acc[nf_], 0, 0, 0);          \
        }                                                                 \
      }                                                                   \
    }                                                                     \
    /* reload W for next step AFTER last use: in flight across stage+barrier */ \
    if ((S) < 7) WLOAD((S) + 1);                                          \
  } while (0)

  STEP(0); STEP(1); STEP(2); STEP(3);
  STEP(4); STEP(5); STEP(6); STEP(7);
#undef STEP
#undef WLOAD

  // ---- epilogue ----
  // C/D layout (verified): col = lane&31, row = (reg&3) + 8*(reg>>2) + 4*(lane>>5)
  float* ex = (float*)(smem + 16384 + wu * 8192);   // [cand 4KB | og 4KB] per wu

  if (wg == 1) {
    // gates {2,3}: cand = ht(ht(x_c)+r_c), og = ht(ht(x_o)+r_o)
    float4 c4[4], o4[4];
#pragma unroll
    for (int r = 0; r < 16; ++r) {
      float cand = htanh(htanh(acc[0][r]) + acc[2][r]);
      float og   = htanh(htanh(acc[1][r]) + acc[3][r]);
      ((float*)&c4[r >> 2])[r & 3] = cand;
      ((float*)&o4[r >> 2])[r & 3] = og;
    }
#pragma unroll
    for (int c = 0; c < 4; ++c) {
      *(float4*)((char*)ex + c * 1024 + lane * 16) = c4[c];
      *(float4*)((char*)ex + 4096 + c * 1024 + lane * 16) = o4[c];
    }
  }
  __syncthreads();
  if (wg == 0) {
    float4 c4[4], o4[4];
#pragma unroll
    for (int c = 0; c < 4; ++c) {
      c4[c] = *(const float4*)((const char*)ex + c * 1024 + lane * 16);
      o4[c] = *(const float4*)((const char*)ex + 4096 + c * 1024 + lane * 16);
    }
#pragma unroll
    for (int r = 0; r < 16; ++r) {
      const int row = (r & 3) + ((r >> 2) << 3) + (lh << 2);
      const int grow = m0 + row;
      const int gu = u0 + wu * 32 + l31;
      // gates {0,1}: f = ht(ht(x_i)+r_f), i = ht(ht(x_f)+r_i)  (note crossing)
      const float fg = htanh(htanh(acc[0][r]) + acc[3][r]);
      const float ig = htanh(htanh(acc[1][r]) + acc[2][r]);
      const float cand = ((const float*)&c4[r >> 2])[r & 3];
      const float og   = ((const float*)&o4[r >> 2])[r & 3];
      const float ct = htanh(cin[grow * 256 + gu]);
      const float cn = fg * ct + ig * cand;
      const float hn = htanh(og * htanh(cn));
      const int o1 = grow * 256 + gu;
      out[o1] = hn;
      out[NB * 256 + o1] = hn;
      out[2 * NB * 256 + o1] = cn;
    }
  }
}

extern "C" void kernel_launch(void* const* d_in, const int* in_sizes, int n_in,
                              void* d_out, int out_size, void* d_ws, size_t ws_size,
                              hipStream_t stream) {
  const float* xin = (const float*)d_in[0];
  const float* hin = (const float*)d_in[1];
  const float* cin = (const float*)d_in[2];
  const float* kf  = (const float*)d_in[3];
  const float* rkf = (const float*)d_in[4];
  float* out = (float*)d_out;

  unsigned short* wfrag = (unsigned short*)d_ws;    // 1024 frags x 1KB = 1MB

  prep_w<<<256, 256, 0, stream>>>(kf, rkf, wfrag);
  blstm_main<<<8192, 256, 0, stream>>>(xin, hin, cin, wfrag, out);
}

// Round 4
// 199.213 us; speedup vs baseline: 2.2328x; 1.0251x over previous
//
#include <hip/hip_runtime.h>

// BinaryLSTMCell fused kernel v4 for MI355X (gfx950).
// B=65536, D=256, U=256. out = [h_new | h_new | c_new], f32.
//
// v3 post-mortem: 230us, MfmaUtil 25% == MFMA-demand/walltime exactly; stalls
// from 3-waves/SIMD occupancy (148 unified regs), 8 fine-grained barrier steps,
// and each wave reading BOTH sides' A-frags (8 ds_read_b128/step).
// v4: side-split waves (4 gates x 1 side each, A-reads halved), k-major
// padded-conflict-free A LDS, 128-unified-reg diet for 4 waves/SIMD, W frags
// direct from L2 with j0 issued pre-barrier, raw lgkm-only barrier (1/step).

#define NB 65536

typedef _Float16 f16x8 __attribute__((ext_vector_type(8)));
typedef float f32x16 __attribute__((ext_vector_type(16)));

__device__ __forceinline__ float htanh(float x) { return fminf(1.f, fmaxf(-1.f, x)); }

// ---------------------------------------------------------------------------
// prep: binarize both weight matrices into 1024 pre-built MFMA B-fragments.
// fragid = ((k16*2 + side)*8 + u32)*4 + gate, 1KB each:
//   lane l holds 16B: n = gate*256 + u32*32 + (l&31), k = k16*16 + (l>>5)*8 + e.
// ---------------------------------------------------------------------------
__global__ void prep_w(const float* __restrict__ Kf, const float* __restrict__ RKf,
                       unsigned short* __restrict__ wfrag) {
  __shared__ unsigned short sgn[32][72];
  const int b = blockIdx.x;            // 256 blocks
  const int side = b >> 7, kt = (b >> 4) & 7, nt = b & 15;
  const float* M = side ? RKf : Kf;
  const int t = threadIdx.x;

  {  // load 32k x 64n tile, coalesced, store signs
    const int k = t >> 3, n8 = (t & 7) << 3;
    const float* p = M + (kt * 32 + k) * 1024 + nt * 64 + n8;
    float4 v0 = *(const float4*)p;
    float4 v1 = *(const float4*)(p + 4);
    float xs[8] = {v0.x, v0.y, v0.z, v0.w, v1.x, v1.y, v1.z, v1.w};
#pragma unroll
    for (int i = 0; i < 8; ++i)
      sgn[k][n8 + i] = (xs[i] >= 0.f) ? 0x3C00u : 0xBC00u;
  }
  __syncthreads();

  // emit 4 fragments (j x u-half), 64 lanes each
  const int fl = t >> 6, l = t & 63;
  const int j = fl >> 1, uhh = fl & 1;
  const int nloc = uhh * 32 + (l & 31);
  const int kloc = j * 16 + (l >> 5) * 8;
  unsigned short o[8];
#pragma unroll
  for (int e = 0; e < 8; ++e) o[e] = sgn[kloc + e][nloc];
  const int ng = nt * 64 + nloc;                 // 0..1023
  const int gate = ng >> 8, u32 = (ng >> 5) & 7;
  const int k16 = kt * 2 + j;                    // 0..15
  const int fragid = ((k16 * 2 + side) * 8 + u32) * 4 + gate;
  uint4 ov;
  ov.x = (unsigned)o[0] | ((unsigned)o[1] << 16);
  ov.y = (unsigned)o[2] | ((unsigned)o[3] << 16);
  ov.z = (unsigned)o[4] | ((unsigned)o[5] << 16);
  ov.w = (unsigned)o[6] | ((unsigned)o[7] << 16);
  *(uint4*)((char*)wfrag + fragid * 1024 + l * 16) = ov;
}

// ---------------------------------------------------------------------------
// main: 256 thr (4 waves: wu x side). Block tile m32 x u64, both sides.
// Wave tile: m32 x (4 gates x 32u) of ONE side; acc = 4 x f32x16 = 64 AGPR.
// K loop: 8 steps of 32 f32-k; A dbuf in LDS k-major f16 hi|lo; W direct L2.
// LDS A: [buf2][side2][chunk8][33 slots][16B] (pad 33 -> conflict-free reads).
// ---------------------------------------------------------------------------
__global__ __launch_bounds__(256, 4)
void blstm_main(const float* __restrict__ xin, const float* __restrict__ hin,
                const float* __restrict__ cin, const unsigned short* __restrict__ wfrag,
                float* __restrict__ out) {
  __shared__ char smem[32768];   // A: [0,16896); epilogue exchange aliases [0,32768)

  const int bid = blockIdx.x;
  const int swz = (bid & 7) * 1024 + (bid >> 3);   // XCD swizzle, 8192 % 8 == 0
  const int m0 = (swz >> 2) << 5;                  // 32-row strip
  const int ub = swz & 3;                          // 64-u block

  const int tid = threadIdx.x;
  const int lane = tid & 63;
  const int w = tid >> 6;
  const int wu = w & 1, sw = w >> 1;               // wave: side sw (0=x,1=r), u32 = ub*2+wu
  const int l31 = lane & 31, lh = lane >> 5;

  // ---- A staging role (wave-uniform side) ----
  const int sSide = tid >> 7;                      // waves 0,1 -> x; 2,3 -> h
  const int sRow = (tid & 127) >> 2;               // 0..31
  const int sQ = tid & 3;                          // 8-f32 piece of the 32-k step
  const float* aPtr = (sSide ? hin : xin) + (m0 + sRow) * 256 + sQ * 8;
  // write: chunk c = sQ (hi) / sQ+4 (lo); byte = side*4224 + (c*33 + sRow)*16
  char* const aWr = smem + sSide * 4224 + sQ * 528 + sRow * 16;   // lo at +2112
  // read: chunk c = hl*4 + j*2 + lh; byte = side*4224 + (c*33 + l31)*16
  const char* const aRd = smem + sw * 4224 + lh * 528 + l31 * 16; // + hl*2112 + j*1056

  // ---- W fragment base (ushort units): byte = (sw*8 + ub*2 + wu)*4096 + lane*16 ----
  const unsigned short* const wq = wfrag + ((sw * 8 + ub * 2 + wu) << 11) + lane * 8;
  // per (s,j): + (s*2+j)*32768 ushorts; per gate: + g*512 ushorts

  f32x16 acc[4] = {};
  f16x8 wf[4];
  f16x8 ah, al;
  float4 a0 = *(const float4*)(aPtr);
  float4 a1 = *(const float4*)(aPtr + 4);

#define MFMA4(AF) do {                                                      \
    acc[0] = __builtin_amdgcn_mfma_f32_32x32x16_f16(AF, wf[0], acc[0], 0, 0, 0); \
    acc[1] = __builtin_amdgcn_mfma_f32_32x32x16_f16(AF, wf[1], acc[1], 0, 0, 0); \
    acc[2] = __builtin_amdgcn_mfma_f32_32x32x16_f16(AF, wf[2], acc[2], 0, 0, 0); \
    acc[3] = __builtin_amdgcn_mfma_f32_32x32x16_f16(AF, wf[3], acc[3], 0, 0, 0); \
  } while (0)

#define STEP(S) do {                                                        \
    /* stage: convert A(S) regs -> LDS buf[S&1]; issue A(S+1) loads */      \
    {                                                                       \
      float xs_[8] = {a0.x, a0.y, a0.z, a0.w, a1.x, a1.y, a1.z, a1.w};      \
      f16x8 hv_, lv_;                                                       \
      _Pragma("unroll")                                                     \
      for (int i_ = 0; i_ < 8; ++i_) {                                      \
        float x_ = xs_[i_];                                                 \
        if (sSide) x_ = htanh(x_);                                          \
        _Float16 hf_ = (_Float16)x_;                                        \
        hv_[i_] = hf_;                                                      \
        lv_[i_] = (_Float16)(x_ - (float)hf_);                              \
      }                                                                     \
      char* wr_ = aWr + ((S) & 1) * 8448;                                   \
      *(f16x8*)(wr_) = hv_;                                                 \
      *(f16x8*)(wr_ + 2112) = lv_;                                          \
    }                                                                       \
    if ((S) < 7) {                                                          \
      a0 = *(const float4*)(aPtr + ((S) + 1) * 32);                         \
      a1 = *(const float4*)(aPtr + ((S) + 1) * 32 + 4);                     \
    }                                                                       \
    /* issue W(S, j0) pre-barrier: stays in flight across it */             \
    {                                                                       \
      const unsigned short* wp_ = wq + ((S) * 2) * 32768;                   \
      wf[0] = *(const f16x8*)(wp_);                                         \
      wf[1] = *(const f16x8*)(wp_ + 512);                                   \
      wf[2] = *(const f16x8*)(wp_ + 1024);                                  \
      wf[3] = *(const f16x8*)(wp_ + 1536);                                  \
    }                                                                       \
    asm volatile("s_waitcnt lgkmcnt(0)\n\ts_barrier" ::: "memory");         \
    {                                                                       \
      const char* rd_ = aRd + ((S) & 1) * 8448;                             \
      ah = *(const f16x8*)(rd_);              /* hl0 j0 */                  \
      al = *(const f16x8*)(rd_ + 2112);       /* hl1 j0 */                  \
      MFMA4(ah);                                                            \
      MFMA4(al);                                                            \
      /* reload same wf regs for j1 (WAR-safe: in-order issue) */           \
      const unsigned short* wp_ = wq + ((S) * 2 + 1) * 32768;               \
      wf[0] = *(const f16x8*)(wp_);                                         \
      wf[1] = *(const f16x8*)(wp_ + 512);                                   \
      wf[2] = *(const f16x8*)(wp_ + 1024);                                  \
      wf[3] = *(const f16x8*)(wp_ + 1536);                                  \
      ah = *(const f16x8*)(rd_ + 1056);        /* hl0 j1 */                 \
      al = *(const f16x8*)(rd_ + 2112 + 1056); /* hl1 j1 */                 \
      MFMA4(ah);                                                            \
      MFMA4(al);                                                            \
    }                                                                       \
  } while (0)

  STEP(0); STEP(1); STEP(2); STEP(3);
  STEP(4); STEP(5); STEP(6); STEP(7);
#undef STEP
#undef MFMA4

  // ---- epilogue ----
  // C/D layout (verified): col = lane&31, row = (reg&3) + 8*(reg>>2) + 4*(lane>>5)
  __syncthreads();   // all K-loop LDS reads done before aliasing A region
  float* ex = (float*)(smem + wu * 16384);  // [gate4][quad4][64 lanes x 16B] per wu

  if (sw == 1) {     // r-waves dump raw acc quads
#pragma unroll
    for (int g = 0; g < 4; ++g)
#pragma unroll
      for (int q = 0; q < 4; ++q) {
        float4 v;
        v.x = acc[g][q * 4 + 0]; v.y = acc[g][q * 4 + 1];
        v.z = acc[g][q * 4 + 2]; v.w = acc[g][q * 4 + 3];
        *(float4*)((char*)ex + (g * 4 + q) * 1024 + lane * 16) = v;
      }
  }
  __syncthreads();
  if (sw == 0) {     // x-waves combine gates and write out
    const int gu = ub * 64 + wu * 32 + l31;
#pragma unroll
    for (int q = 0; q < 4; ++q) {
      float4 ri = *(const float4*)((const char*)ex + (0 * 4 + q) * 1024 + lane * 16);
      float4 rf = *(const float4*)((const char*)ex + (1 * 4 + q) * 1024 + lane * 16);
      float4 rc = *(const float4*)((const char*)ex + (2 * 4 + q) * 1024 + lane * 16);
      float4 ro = *(const float4*)((const char*)ex + (3 * 4 + q) * 1024 + lane * 16);
#pragma unroll
      for (int t = 0; t < 4; ++t) {
        const int r = q * 4 + t;
        const int row = t + q * 8 + lh * 4;
        const int grow = m0 + row;
        const float xi = htanh(acc[0][r]);
        const float xf = htanh(acc[1][r]);
        const float xc = htanh(acc[2][r]);
        const float xo = htanh(acc[3][r]);
        const float riv = ((const float*)&ri)[t];
        const float rfv = ((const float*)&rf)[t];
        const float rcv = ((const float*)&rc)[t];
        const float rov = ((const float*)&ro)[t];
        // reference gate crossing: f = ht(x_i + r_f), i = ht(x_f + r_i)
        const float fg   = htanh(xi + rfv);
        const float ig   = htanh(xf + riv);
        const float cand = htanh(xc + rcv);
        const float og   = htanh(xo + rov);
        const float ct = htanh(cin[grow * 256 + gu]);
        const float cn = fg * ct + ig * cand;
        const float hn = htanh(og * htanh(cn));
        const int o1 = grow * 256 + gu;
        out[o1] = hn;
        out[NB * 256 + o1] = hn;
        out[2 * NB * 256 + o1] = cn;
      }
    }
  }
}

extern "C" void kernel_launch(void* const* d_in, const int* in_sizes, int n_in,
                              void* d_out, int out_size, void* d_ws, size_t ws_size,
                              hipStream_t stream) {
  const float* xin = (const float*)d_in[0];
  const float* hin = (const float*)d_in[1];
  const float* cin = (const float*)d_in[2];
  const float* kf  = (const float*)d_in[3];
  const float* rkf = (const float*)d_in[4];
  float* out = (float*)d_out;

  unsigned short* wfrag = (unsigned short*)d_ws;    // 1024 frags x 1KB = 1MB

  prep_w<<<256, 256, 0, stream>>>(kf, rkf, wfrag);
  blstm_main<<<8192, 256, 0, stream>>>(xin, hin, cin, wfrag, out);
}